// Round 8
// baseline (269.036 us; speedup 1.0000x reference)
//
#include <hip/hip_runtime.h>

// MS-G3D block. Split GEMM with fragment-layout intermediate (no gathers):
//  k1a: TMP^T-GEMM (MLP), writes TMP in exact MFMA A-frag order (coalesced).
//  k1b: agg GEMM, zero LDS, streams TMP A-frags + broadcast B-frags.
// N=8, C=96, T=128, V=25, WIN=3, VL=75, NS=6.

#define NB 8
#define CB 96
#define TB 128
#define VB 25
#define VLB 75
#define EPSB 1e-5f
#define XRS 104   // xraw row stride (shorts)
#define HBS 296   // hnb row stride (shorts)

typedef __attribute__((ext_vector_type(8))) short bf16x8;
typedef __attribute__((ext_vector_type(4))) float f32x4;

__device__ inline unsigned short f2bf(float f) {
  unsigned int u = __float_as_uint(f);
  u = (u + 0x7FFFu + ((u >> 16) & 1u)) >> 16;
  return (unsigned short)u;
}
__device__ inline float bf2f(unsigned short u) {
  return __uint_as_float(((unsigned int)u) << 16);
}
__device__ inline unsigned int packbf(float lo, float hi) {
  return (unsigned int)f2bf(lo) | ((unsigned int)f2bf(hi) << 16);
}

// ---------------- K0: build swizzled weights; zero stats ----------------
// Wsw2 [mt<72][kk<3][512]: W'[m=mt*16+(lane&15)][c=kk*32+(lane>>4)*8+j],
//      m=(ps,o96): ps=mt/6, o96=(mt%6)*16+(lane&15)
// Bsw2 [ut<5][kk<30][512]: ABcat[u=ut*16+(lane&15)][k=kk*32+(lane>>4)*8+j],
//      k=(ps,u'): ps=k/80, u'=k%80
// Wosw [wave<6][kk<9][512]: Wo[o][k] fragment order
__global__ __launch_bounds__(256) void k0_init(
    const float* __restrict__ As, const float* __restrict__ Bs,
    const float* __restrict__ Ar, const float* __restrict__ Wm,
    const float* __restrict__ Wo,
    unsigned short* __restrict__ Wsw2, unsigned short* __restrict__ Bsw2,
    unsigned short* __restrict__ Wosw, float* __restrict__ stats) {
  int i = blockIdx.x * 256 + threadIdx.x;
  if (i < 110592) {                     // Wsw2: 72*3*512
    int mt = i / 1536, r = i % 1536;
    int kk = r / 512, r3 = r % 512;
    int lane = r3 / 8, j = r3 % 8;
    int ps = mt / 6;
    int o96 = (mt % 6) * 16 + (lane & 15);
    int c = kk * 32 + (lane >> 4) * 8 + j;
    Wsw2[i] = f2bf(Wm[o96 * 1152 + ps * 96 + c]);
  }
  if (i < 76800) {                      // Bsw2: 5*30*512
    int ut = i / 15360, r = i % 15360;
    int kk = r / 512, r3 = r % 512;
    int lane = r3 / 8, j = r3 % 8;
    int u = ut * 16 + (lane & 15);
    int k = kk * 32 + (lane >> 4) * 8 + j;
    int ps = k / 80, up = k % 80;
    float v = 0.f;
    if (u < 75 && up < 75) {
      int path = ps / 6, s = ps % 6;
      int idx = (s * 75 + u) * 75 + up;
      v = (path == 0 ? As[idx] : Bs[idx]) + Ar[idx];
    }
    Bsw2[i] = f2bf(v);
  }
  if (i < 27648) {                      // Wosw: 6*9*512
    int wv = i / 4608, r = i % 4608;
    int kk = r / 512, r3 = r % 512;
    int lane = r3 / 8, j = r3 % 8;
    int o = wv * 16 + (lane & 15);
    int k = kk * 32 + (lane >> 4) * 8 + j;
    Wosw[i] = f2bf(Wo[o * 288 + k]);
  }
  if (i < 384) stats[i] = 0.f;
}

// ---------------- K1a: transposed MLP GEMM -> TMP in A-frag layout ----------
// grid = 1024 nt * 3 mblk, 384 thr (6 waves). Wave owns 4 m-tiles x 5 u'-tiles.
// D[u'][m] = sum_c xu^T[u'][c] * W'^T[c][m];  TMP[nt][ot96][kk][512] A-frag order.
__global__ __launch_bounds__(384, 2) void k1a(
    const float* __restrict__ x, const unsigned short* __restrict__ Wsw2,
    unsigned short* __restrict__ TMP) {
  __shared__ unsigned short xraw[80 * XRS];   // [u'][c], rows 75..79 zero
  const int tid = threadIdx.x;
  const int nt = blockIdx.x / 3, mblk = blockIdx.x % 3;
  const int n = nt >> 7, t = nt & 127;
  const int wave = tid >> 6, lane = tid & 63;
  const int l15 = lane & 15, quad = lane >> 4, q8 = quad * 8;

  for (int idx = tid; idx < 96 * 80; idx += 384) {
    int c = idx / 80, r = idx - c * 80;
    float v = 0.f;
    if (r < 75) {
      int tt = t - 1 + r / 25, vv = r % 25;
      if (tt >= 0 && tt < TB) v = x[((n * CB + c) * TB + tt) * VB + vv];
    }
    xraw[r * XRS + c] = f2bf(v);
  }
  __syncthreads();

  // B-frags: 4 m-tiles x 3 kk, coalesced dwordx4
  const int mt0 = mblk * 24 + wave * 4;
  bf16x8 bf[4][3];
#pragma unroll
  for (int i = 0; i < 4; ++i)
#pragma unroll
    for (int kk = 0; kk < 3; ++kk)
      bf[i][kk] = *reinterpret_cast<const bf16x8*>(Wsw2 + ((mt0 + i) * 3 + kk) * 512 + lane * 8);

  const f32x4 zf = {0.f, 0.f, 0.f, 0.f};
  f32x4 acc[4][5];
#pragma unroll
  for (int i = 0; i < 4; ++i)
#pragma unroll
    for (int ut = 0; ut < 5; ++ut) acc[i][ut] = zf;

#pragma unroll
  for (int ut = 0; ut < 5; ++ut)
#pragma unroll
    for (int kk = 0; kk < 3; ++kk) {
      bf16x8 a = *reinterpret_cast<const bf16x8*>(&xraw[(ut * 16 + l15) * XRS + kk * 32 + q8]);
#pragma unroll
      for (int i = 0; i < 4; ++i)
        acc[i][ut] = __builtin_amdgcn_mfma_f32_16x16x32_bf16(a, bf[i][kk], acc[i][ut], 0, 0, 0);
    }

  // store: lane's 4 accs (u' = ut*16+quad*4+r, m fixed = mt*16+l15) -> one dwordx2
#pragma unroll
  for (int i = 0; i < 4; ++i) {
    const int mt = mt0 + i;
    const int ps = mt / 6, ot96 = mt % 6;
    unsigned short* base = TMP + (unsigned long long)(nt * 6 + ot96) * 15360;  // 30*512
#pragma unroll
    for (int ut = 0; ut < 5; ++ut) {
      int ktb = ps * 80 + ut * 16 + quad * 4;       // k_tmp of reg 0
      int off = (ktb >> 5) * 512 + ((ktb >> 3) & 3) * 128 + l15 * 8 + (ktb & 7);
      unsigned int d0 = packbf(acc[i][ut][0], acc[i][ut][1]);
      unsigned int d1 = packbf(acc[i][ut][2], acc[i][ut][3]);
      *reinterpret_cast<uint2*>(base + off) = make_uint2(d0, d1);
    }
  }
}

// ---------------- K1b: agg GEMM, zero LDS staging, pure streaming -----------
// grid = 1024 (1 nt), 384 thr. Wave w = o-tile w; 5 u-tiles; K=960 (30 steps).
__global__ __launch_bounds__(384) void k1b(
    const unsigned short* __restrict__ TMP, const unsigned short* __restrict__ Bsw2,
    const float* __restrict__ bm, unsigned short* __restrict__ h_relu,
    float* __restrict__ stats1) {
  __shared__ float st1s[96], st2s[96];
  const int tid = threadIdx.x;
  const int nt = blockIdx.x, n = nt >> 7, t = nt & 127;
  const int wave = tid >> 6, lane = tid & 63;
  const int l15 = lane & 15, quad = lane >> 4;
  const unsigned short* Ap = TMP + (unsigned long long)(nt * 6 + wave) * 15360 + lane * 8;
  const unsigned short* Bp = Bsw2 + lane * 8;

  const f32x4 zf = {0.f, 0.f, 0.f, 0.f};
  f32x4 acc[5];
#pragma unroll
  for (int ut = 0; ut < 5; ++ut) acc[ut] = zf;

#pragma unroll 6
  for (int kk = 0; kk < 30; ++kk) {
    bf16x8 a = *reinterpret_cast<const bf16x8*>(Ap + kk * 512);
#pragma unroll
    for (int ut = 0; ut < 5; ++ut) {
      bf16x8 b = *reinterpret_cast<const bf16x8*>(Bp + (ut * 30 + kk) * 512);
      acc[ut] = __builtin_amdgcn_mfma_f32_16x16x32_bf16(a, b, acc[ut], 0, 0, 0);
    }
  }

  // epilogue: bias + relu + bf16 store + BN1 partial stats
  const int orow = wave * 16 + quad * 4;
  float s1[4] = {0.f, 0.f, 0.f, 0.f}, s2[4] = {0.f, 0.f, 0.f, 0.f};
#pragma unroll
  for (int r = 0; r < 4; ++r) {
    const int o = orow + r;
    const float bias = bm[o];
    unsigned short* hp = h_relu + ((n * CB + o) * TB + t) * VLB;
#pragma unroll
    for (int ut = 0; ut < 5; ++ut) {
      int u = ut * 16 + l15;
      if (u < VLB) {
        float v = acc[ut][r] + bias;
        v = v > 0.f ? v : 0.f;
        hp[u] = f2bf(v);
        s1[r] += v;
        s2[r] += v * v;
      }
    }
  }
#pragma unroll
  for (int off = 1; off < 16; off <<= 1) {
#pragma unroll
    for (int r = 0; r < 4; ++r) {
      s1[r] += __shfl_xor(s1[r], off, 64);
      s2[r] += __shfl_xor(s2[r], off, 64);
    }
  }
  if (l15 == 0) {
#pragma unroll
    for (int r = 0; r < 4; ++r) { st1s[orow + r] = s1[r]; st2s[orow + r] = s2[r]; }
  }
  __syncthreads();
  if (tid < 96) {
    atomicAdd(&stats1[tid], st1s[tid]);
    atomicAdd(&stats1[96 + tid], st2s[tid]);
  }
}

// ---------------- K3: BN1-finalize + relu + out_conv (MFMA, 2 t/blk) --------
__global__ __launch_bounds__(384) void k3n(
    const unsigned short* __restrict__ h_relu, const float* __restrict__ stats1,
    const float* __restrict__ g1, const float* __restrict__ bt1,
    const unsigned short* __restrict__ Wosw, const float* __restrict__ bo,
    float* __restrict__ out_pre, float* __restrict__ stats2) {
  __shared__ unsigned short hnb[2][32 * HBS];
  __shared__ float a1s[96], b1s[96];
  __shared__ float st1[96], st2[96];
  const int tid = threadIdx.x;
  const int n = blockIdx.x >> 6, t0 = (blockIdx.x & 63) * 2;

  if (tid < 96) {
    const float inv = 1.f / (8.f * 128.f * 75.f);
    float m = stats1[tid] * inv;
    float var = stats1[96 + tid] * inv - m * m;
    float a = g1[tid] * rsqrtf(var + EPSB);
    a1s[tid] = a;
    b1s[tid] = bt1[tid] - m * a;
  }
  for (int idx = tid; idx < 2 * 7 * HBS; idx += 384) {
    int d = idx / (7 * HBS), rm = idx % (7 * HBS);
    hnb[d][25 * HBS + rm] = 0;
  }
  __syncthreads();

  for (int idx = tid; idx < 2 * 96 * 75; idx += 384) {
    int d = idx / 7200, rm = idx % 7200;
    int i = rm / 75, u = rm - i * 75;
    float hv = bf2f(h_relu[((n * CB + i) * TB + t0 + d) * VLB + u]);
    float v = a1s[i] * hv + b1s[i];
    v = v > 0.f ? v : 0.f;
    int w = u / 25, vv = u - w * 25;
    hnb[d][vv * HBS + i * 3 + w] = f2bf(v);
  }
  __syncthreads();

  const int wave = tid >> 6, lane = tid & 63;
  const int l15 = lane & 15, quad = lane >> 4, q8 = quad * 8;
  const f32x4 zf = {0.f, 0.f, 0.f, 0.f};
  f32x4 acc[2][2] = {{zf, zf}, {zf, zf}};
  const unsigned short* Apw = Wosw + wave * 4608 + lane * 8;
#pragma unroll
  for (int kk = 0; kk < 9; ++kk) {
    bf16x8 a = *reinterpret_cast<const bf16x8*>(Apw + kk * 512);
#pragma unroll
    for (int d = 0; d < 2; ++d) {
      bf16x8 b0 = *reinterpret_cast<const bf16x8*>(&hnb[d][l15 * HBS + kk * 32 + q8]);
      bf16x8 b1 = *reinterpret_cast<const bf16x8*>(&hnb[d][(16 + l15) * HBS + kk * 32 + q8]);
      acc[d][0] = __builtin_amdgcn_mfma_f32_16x16x32_bf16(a, b0, acc[d][0], 0, 0, 0);
      acc[d][1] = __builtin_amdgcn_mfma_f32_16x16x32_bf16(a, b1, acc[d][1], 0, 0, 0);
    }
  }

  const int orow = wave * 16 + quad * 4;
  float s1[4] = {0.f, 0.f, 0.f, 0.f}, s2[4] = {0.f, 0.f, 0.f, 0.f};
#pragma unroll
  for (int d = 0; d < 2; ++d) {
#pragma unroll
    for (int ntl = 0; ntl < 2; ++ntl) {
      int v = ntl * 16 + l15;
      if (v < VB) {
#pragma unroll
        for (int r = 0; r < 4; ++r) {
          const int o = orow + r;
          float val = acc[d][ntl][r] + bo[o];
          out_pre[((n * CB + o) * TB + t0 + d) * VB + v] = val;
          s1[r] += val;
          s2[r] += val * val;
        }
      }
    }
  }
#pragma unroll
  for (int off = 1; off < 16; off <<= 1) {
#pragma unroll
    for (int r = 0; r < 4; ++r) {
      s1[r] += __shfl_xor(s1[r], off, 64);
      s2[r] += __shfl_xor(s2[r], off, 64);
    }
  }
  if (l15 == 0) {
#pragma unroll
    for (int r = 0; r < 4; ++r) { st1[orow + r] = s1[r]; st2[orow + r] = s2[r]; }
  }
  __syncthreads();
  if (tid < 96) {
    atomicAdd(&stats2[tid], st1[tid]);
    atomicAdd(&stats2[96 + tid], st2[tid]);
  }
}

// ---------------- K5: BN2 finalize (float4 elementwise) ----------------
__global__ __launch_bounds__(256) void k5_bn2(
    const float* __restrict__ out_pre, const float* __restrict__ stats2,
    const float* __restrict__ g2, const float* __restrict__ bt2,
    float* __restrict__ out) {
  int idx = blockIdx.x * 256 + threadIdx.x;
  if (idx >= NB * CB * TB * VB / 4) return;
  int o = (idx / (TB * VB / 4)) % CB;
  const float inv = 1.f / (8.f * 128.f * 25.f);
  float m = stats2[o] * inv;
  float var = stats2[96 + o] * inv - m * m;
  float a = g2[o] * rsqrtf(var + EPSB);
  float b = bt2[o] - m * a;
  f32x4 vin = reinterpret_cast<const f32x4*>(out_pre)[idx];
  f32x4 vo;
#pragma unroll
  for (int j = 0; j < 4; ++j) vo[j] = a * vin[j] + b;
  reinterpret_cast<f32x4*>(out)[idx] = vo;
}

extern "C" void kernel_launch(void* const* d_in, const int* in_sizes, int n_in,
                              void* d_out, int out_size, void* d_ws, size_t ws_size,
                              hipStream_t stream) {
  const float* x   = (const float*)d_in[0];
  const float* As  = (const float*)d_in[1];
  const float* Bs  = (const float*)d_in[2];
  const float* Ar  = (const float*)d_in[3];
  const float* Wm  = (const float*)d_in[4];
  const float* bm  = (const float*)d_in[5];
  const float* g1  = (const float*)d_in[6];
  const float* bt1 = (const float*)d_in[7];
  const float* Wo  = (const float*)d_in[8];
  const float* bo  = (const float*)d_in[9];
  const float* g2  = (const float*)d_in[10];
  const float* bt2 = (const float*)d_in[11];
  float* out = (float*)d_out;

  char* base = (char*)d_ws;
  unsigned short* TMP  = (unsigned short*)base;                  // 188,743,680 B
  unsigned short* HR   = (unsigned short*)(base + 188743680);    //  14,745,600 B
  float* out_pre       = (float*)(base + 203489280);             //   9,830,400 B
  unsigned short* Wsw2 = (unsigned short*)(base + 213319680);    //     221,184 B
  unsigned short* Bsw2 = (unsigned short*)(base + 213540864);    //     153,600 B
  unsigned short* Wosw = (unsigned short*)(base + 213694464);    //      55,296 B
  float* stats         = (float*)(base + 213749760);             //       1,536 B
  float* stats1 = stats, *stats2 = stats + 192;

  k0_init<<<432, 256, 0, stream>>>(As, Bs, Ar, Wm, Wo, Wsw2, Bsw2, Wosw, stats);
  k1a<<<1024 * 3, 384, 0, stream>>>(x, Wsw2, TMP);
  k1b<<<1024, 384, 0, stream>>>(TMP, Bsw2, bm, HR, stats1);
  k3n<<<NB * TB / 2, 384, 0, stream>>>(HR, stats1, g1, bt1, Wosw, bo, out_pre, stats2);
  k5_bn2<<<(NB * CB * TB * VB / 4 + 255) / 256, 256, 0, stream>>>(out_pre, stats2, g2, bt2, out);
}

// Round 9
// 249.938 us; speedup vs baseline: 1.0764x; 1.0764x over previous
//
#include <hip/hip_runtime.h>

// MS-G3D block. Fused bf16-MFMA k1: transposed GEMM1 + register-space C->B
// transform (ds_bpermute), zero LDS round-trip, zero barriers in ps loop.
// N=8, C=96, T=128, V=25, WIN=3, VL=75, NS=6.

#define NB 8
#define CB 96
#define TB 128
#define VB 25
#define VLB 75
#define EPSB 1e-5f
#define XRS 104   // xraw row stride (shorts)
#define HBS 296   // hnb row stride (shorts)
#define HRS 80    // h_relu row stride (shorts) -> 160B rows, 8B-aligned vec stores

typedef __attribute__((ext_vector_type(8))) short bf16x8;
typedef __attribute__((ext_vector_type(4))) float f32x4;

__device__ inline unsigned short f2bf(float f) {
  unsigned int u = __float_as_uint(f);
  u = (u + 0x7FFFu + ((u >> 16) & 1u)) >> 16;
  return (unsigned short)u;
}
__device__ inline float bf2f(unsigned short u) {
  return __uint_as_float(((unsigned int)u) << 16);
}
// pack two f32 -> dword of two bf16 (round-half-up via +0x8000, then v_perm)
__device__ inline unsigned int pack2(float lo, float hi) {
  unsigned int a = __float_as_uint(hi) + 0x8000u;
  unsigned int b = __float_as_uint(lo) + 0x8000u;
  return __builtin_amdgcn_perm(a, b, 0x07060302u);
}

// ---------------- K0: fragment-swizzled bf16 weights; zero stats -------------
// Wsw  [ps][wave][kk][512]: W_ps[o=wv*16+(lane&15)][c=kk*32+(lane>>4)*8+j]
// ABsw [ps][ut][kk][512]  : AB_ps[u=ut*16+(lane&15)][u'=kk*32+(lane>>4)*8+j]
// Wosw [wave][kk][512]    : Wo[o][k] fragment order
__global__ __launch_bounds__(256) void k0_init(
    const float* __restrict__ As, const float* __restrict__ Bs,
    const float* __restrict__ Ar, const float* __restrict__ Wm,
    const float* __restrict__ Wo,
    unsigned short* __restrict__ ABsw, unsigned short* __restrict__ Wsw,
    unsigned short* __restrict__ Wosw, float* __restrict__ stats) {
  int i = blockIdx.x * 256 + threadIdx.x;
  if (i < 110592) {                     // Wsw: 12*6*3*512
    int ps = i / 9216, r = i % 9216;
    int wv = r / 1536, r2 = r % 1536;
    int kk = r2 / 512, r3 = r2 % 512;
    int lane = r3 / 8, j = r3 % 8;
    int o = wv * 16 + (lane & 15);
    int c = kk * 32 + (lane >> 4) * 8 + j;
    Wsw[i] = f2bf(Wm[o * 1152 + ps * 96 + c]);
  }
  if (i < 92160) {                      // ABsw: 12*5*3*512
    int ps = i / 7680, r = i % 7680;
    int ut = r / 1536, r2 = r % 1536;
    int kk = r2 / 512, r3 = r2 % 512;
    int lane = r3 / 8, j = r3 % 8;
    int u = ut * 16 + (lane & 15);
    int up = kk * 32 + (lane >> 4) * 8 + j;
    float v = 0.f;
    if (u < 75 && up < 75) {
      int path = ps / 6, s = ps % 6;
      int idx = (s * 75 + u) * 75 + up;
      v = (path == 0 ? As[idx] : Bs[idx]) + Ar[idx];
    }
    ABsw[i] = f2bf(v);
  }
  if (i < 27648) {                      // Wosw: 6*9*512
    int wv = i / 4608, r = i % 4608;
    int kk = r / 512, r3 = r % 512;
    int lane = r3 / 8, j = r3 % 8;
    int o = wv * 16 + (lane & 15);
    int k = kk * 32 + (lane >> 4) * 8 + j;
    Wosw[i] = f2bf(Wo[o * 288 + k]);
  }
  if (i < 384) stats[i] = 0.f;
}

// ---------------- K1: fused (MLP^T -> bpermute -> agg^T) x12 -----------------
// grid = N*T = 1024, 384 thr (6 waves). Wave w owns o-cols [16w,16w+16).
// Per ps: D'[u'][o]=mfma(x,w) -> pack -> 20 bpermute -> D2[u][o]+=mfma(AB,B2).
__global__ __launch_bounds__(384, 3) void k1r(
    const float* __restrict__ x, const unsigned short* __restrict__ ABsw,
    const unsigned short* __restrict__ Wsw, const float* __restrict__ bm,
    unsigned short* __restrict__ h_relu, float* __restrict__ stats1) {
  __shared__ unsigned short xraw[80 * XRS];   // [u'][c], rows 75..79 zero
  __shared__ float st1s[96], st2s[96];
  const int tid = threadIdx.x;
  const int n = blockIdx.x >> 7, t = blockIdx.x & 127;
  const int wave = tid >> 6, lane = tid & 63;
  const int l15 = lane & 15, quad = lane >> 4, q8 = quad * 8;

  for (int idx = tid; idx < 96 * 80; idx += 384) {
    int c = idx / 80, r = idx - c * 80;
    float v = 0.f;
    if (r < 75) {
      int tt = t - 1 + r / 25, vv = r % 25;
      if (tt >= 0 && tt < TB) v = x[((n * CB + c) * TB + tt) * VB + vv];
    }
    xraw[r * XRS + c] = f2bf(v);
  }
  __syncthreads();

  const f32x4 zf = {0.f, 0.f, 0.f, 0.f};
  f32x4 acc2[5];
#pragma unroll
  for (int ut = 0; ut < 5; ++ut) acc2[ut] = zf;

  const unsigned short* Wbase = Wsw + wave * 1536 + lane * 8;
  const unsigned short* Bbase = ABsw + lane * 8;
  const int srcA = ((2 * (quad & 1)) * 16 + l15) * 4;        // for w=0,1
  const int srcB = ((2 * (quad & 1) + 1) * 16 + l15) * 4;    // for w=2,3
  const bool hiq = (quad >> 1) != 0;

  for (int ps = 0; ps < 12; ++ps) {
    bf16x8 wa[3];
#pragma unroll
    for (int kk = 0; kk < 3; ++kk)
      wa[kk] = *reinterpret_cast<const bf16x8*>(Wbase + ps * 9216 + kk * 512);

    // GEMM1 transposed: D'[u'][o] = sum_c xu^T[u'][c] * W[c][o]
    f32x4 acc1[5];
#pragma unroll
    for (int ut = 0; ut < 5; ++ut) acc1[ut] = zf;
#pragma unroll
    for (int kk = 0; kk < 3; ++kk)
#pragma unroll
      for (int ut = 0; ut < 5; ++ut) {
        bf16x8 xa = *reinterpret_cast<const bf16x8*>(&xraw[(ut * 16 + l15) * XRS + kk * 32 + q8]);
        acc1[ut] = __builtin_amdgcn_mfma_f32_16x16x32_bf16(xa, wa[kk], acc1[ut], 0, 0, 0);
      }
    // pack: dw[tile][i] = bf16 pair (rows quad*4+2i, +2i+1; col o=l15)
    int dw[5][2];
#pragma unroll
    for (int ut = 0; ut < 5; ++ut) {
      dw[ut][0] = pack2(acc1[ut][0], acc1[ut][1]);
      dw[ut][1] = pack2(acc1[ut][2], acc1[ut][3]);
    }
    // GEMM2: D2[u][o] += AB[u][u'] * tmp'[u'][o]; B2 built by bpermute
#pragma unroll
    for (int kk = 0; kk < 3; ++kk) {
      int bi[4];
#pragma unroll
      for (int w = 0; w < 4; ++w) {
        int src = (w < 2) ? srcA : srcB;
        int rA = __builtin_amdgcn_ds_bpermute(src, dw[2 * kk][w & 1]);
        int rB = (kk < 2) ? __builtin_amdgcn_ds_bpermute(src, dw[2 * kk + 1][w & 1]) : 0;
        bi[w] = hiq ? rB : rA;
      }
      bf16x8 b2 = *reinterpret_cast<bf16x8*>(bi);
#pragma unroll
      for (int ut = 0; ut < 5; ++ut) {
        bf16x8 ab = *reinterpret_cast<const bf16x8*>(Bbase + ps * 7680 + (ut * 3 + kk) * 512);
        acc2[ut] = __builtin_amdgcn_mfma_f32_16x16x32_bf16(ab, b2, acc2[ut], 0, 0, 0);
      }
    }
  }

  // epilogue: bias+relu+vec store (stride-80 rows; u>=75 junk unread) + stats
  const int o = wave * 16 + l15;
  const float bias = bm[o];
  unsigned short* hp = h_relu + ((n * CB + o) * TB + t) * HRS;
  float s1 = 0.f, s2 = 0.f;
#pragma unroll
  for (int ut = 0; ut < 5; ++ut) {
    float vr[4];
#pragma unroll
    for (int r = 0; r < 4; ++r) {
      float v = acc2[ut][r] + bias;
      vr[r] = v > 0.f ? v : 0.f;
      int u = ut * 16 + quad * 4 + r;
      if (u < VLB) { s1 += vr[r]; s2 += vr[r] * vr[r]; }
    }
    *reinterpret_cast<uint2*>(hp + ut * 16 + quad * 4) =
        make_uint2(pack2(vr[0], vr[1]), pack2(vr[2], vr[3]));
  }
  s1 += __shfl_xor(s1, 16, 64); s2 += __shfl_xor(s2, 16, 64);
  s1 += __shfl_xor(s1, 32, 64); s2 += __shfl_xor(s2, 32, 64);
  if (quad == 0) { st1s[o] = s1; st2s[o] = s2; }
  __syncthreads();
  if (tid < 96) {
    atomicAdd(&stats1[tid], st1s[tid]);
    atomicAdd(&stats1[96 + tid], st2s[tid]);
  }
}

// ---------------- K3: BN1-finalize + relu + out_conv (MFMA, 2 t/blk) --------
__global__ __launch_bounds__(384) void k3n(
    const unsigned short* __restrict__ h_relu, const float* __restrict__ stats1,
    const float* __restrict__ g1, const float* __restrict__ bt1,
    const unsigned short* __restrict__ Wosw, const float* __restrict__ bo,
    float* __restrict__ out_pre, float* __restrict__ stats2) {
  __shared__ unsigned short hnb[2][32 * HBS];
  __shared__ float a1s[96], b1s[96];
  __shared__ float st1[96], st2[96];
  const int tid = threadIdx.x;
  const int n = blockIdx.x >> 6, t0 = (blockIdx.x & 63) * 2;

  if (tid < 96) {
    const float inv = 1.f / (8.f * 128.f * 75.f);
    float m = stats1[tid] * inv;
    float var = stats1[96 + tid] * inv - m * m;
    float a = g1[tid] * rsqrtf(var + EPSB);
    a1s[tid] = a;
    b1s[tid] = bt1[tid] - m * a;
  }
  for (int idx = tid; idx < 2 * 7 * HBS; idx += 384) {
    int d = idx / (7 * HBS), rm = idx % (7 * HBS);
    hnb[d][25 * HBS + rm] = 0;
  }
  __syncthreads();

  for (int idx = tid; idx < 2 * 96 * 75; idx += 384) {
    int d = idx / 7200, rm = idx % 7200;
    int i = rm / 75, u = rm - i * 75;
    float hv = bf2f(h_relu[((n * CB + i) * TB + t0 + d) * HRS + u]);
    float v = a1s[i] * hv + b1s[i];
    v = v > 0.f ? v : 0.f;
    int w = u / 25, vv = u - w * 25;
    hnb[d][vv * HBS + i * 3 + w] = f2bf(v);
  }
  __syncthreads();

  const int wave = tid >> 6, lane = tid & 63;
  const int l15 = lane & 15, quad = lane >> 4, q8 = quad * 8;
  const f32x4 zf = {0.f, 0.f, 0.f, 0.f};
  f32x4 acc[2][2] = {{zf, zf}, {zf, zf}};
  const unsigned short* Apw = Wosw + wave * 4608 + lane * 8;
#pragma unroll
  for (int kk = 0; kk < 9; ++kk) {
    bf16x8 a = *reinterpret_cast<const bf16x8*>(Apw + kk * 512);
#pragma unroll
    for (int d = 0; d < 2; ++d) {
      bf16x8 b0 = *reinterpret_cast<const bf16x8*>(&hnb[d][l15 * HBS + kk * 32 + q8]);
      bf16x8 b1 = *reinterpret_cast<const bf16x8*>(&hnb[d][(16 + l15) * HBS + kk * 32 + q8]);
      acc[d][0] = __builtin_amdgcn_mfma_f32_16x16x32_bf16(a, b0, acc[d][0], 0, 0, 0);
      acc[d][1] = __builtin_amdgcn_mfma_f32_16x16x32_bf16(a, b1, acc[d][1], 0, 0, 0);
    }
  }

  const int orow = wave * 16 + quad * 4;
  float s1[4] = {0.f, 0.f, 0.f, 0.f}, s2[4] = {0.f, 0.f, 0.f, 0.f};
#pragma unroll
  for (int d = 0; d < 2; ++d) {
#pragma unroll
    for (int ntl = 0; ntl < 2; ++ntl) {
      int v = ntl * 16 + l15;
      if (v < VB) {
#pragma unroll
        for (int r = 0; r < 4; ++r) {
          const int o = orow + r;
          float val = acc[d][ntl][r] + bo[o];
          out_pre[((n * CB + o) * TB + t0 + d) * VB + v] = val;
          s1[r] += val;
          s2[r] += val * val;
        }
      }
    }
  }
#pragma unroll
  for (int off = 1; off < 16; off <<= 1) {
#pragma unroll
    for (int r = 0; r < 4; ++r) {
      s1[r] += __shfl_xor(s1[r], off, 64);
      s2[r] += __shfl_xor(s2[r], off, 64);
    }
  }
  if (l15 == 0) {
#pragma unroll
    for (int r = 0; r < 4; ++r) { st1[orow + r] = s1[r]; st2[orow + r] = s2[r]; }
  }
  __syncthreads();
  if (tid < 96) {
    atomicAdd(&stats2[tid], st1[tid]);
    atomicAdd(&stats2[96 + tid], st2[tid]);
  }
}

// ---------------- K5: BN2 finalize (float4 elementwise) ----------------
__global__ __launch_bounds__(256) void k5_bn2(
    const float* __restrict__ out_pre, const float* __restrict__ stats2,
    const float* __restrict__ g2, const float* __restrict__ bt2,
    float* __restrict__ out) {
  int idx = blockIdx.x * 256 + threadIdx.x;
  if (idx >= NB * CB * TB * VB / 4) return;
  int o = (idx / (TB * VB / 4)) % CB;
  const float inv = 1.f / (8.f * 128.f * 25.f);
  float m = stats2[o] * inv;
  float var = stats2[96 + o] * inv - m * m;
  float a = g2[o] * rsqrtf(var + EPSB);
  float b = bt2[o] - m * a;
  f32x4 vin = reinterpret_cast<const f32x4*>(out_pre)[idx];
  f32x4 vo;
#pragma unroll
  for (int j = 0; j < 4; ++j) vo[j] = a * vin[j] + b;
  reinterpret_cast<f32x4*>(out)[idx] = vo;
}

extern "C" void kernel_launch(void* const* d_in, const int* in_sizes, int n_in,
                              void* d_out, int out_size, void* d_ws, size_t ws_size,
                              hipStream_t stream) {
  const float* x   = (const float*)d_in[0];
  const float* As  = (const float*)d_in[1];
  const float* Bs  = (const float*)d_in[2];
  const float* Ar  = (const float*)d_in[3];
  const float* Wm  = (const float*)d_in[4];
  const float* bm  = (const float*)d_in[5];
  const float* g1  = (const float*)d_in[6];
  const float* bt1 = (const float*)d_in[7];
  const float* Wo  = (const float*)d_in[8];
  const float* bo  = (const float*)d_in[9];
  const float* g2  = (const float*)d_in[10];
  const float* bt2 = (const float*)d_in[11];
  float* out = (float*)d_out;

  char* base = (char*)d_ws;
  unsigned short* HR   = (unsigned short*)base;                  // 15,728,640 B
  float* out_pre       = (float*)(base + 15728640);              //  9,830,400 B
  unsigned short* ABsw = (unsigned short*)(base + 25559040);     //    184,320 B
  unsigned short* Wsw  = (unsigned short*)(base + 25743360);     //    221,184 B
  unsigned short* Wosw = (unsigned short*)(base + 25964544);     //     55,296 B
  float* stats         = (float*)(base + 26019840);              //      1,536 B
  float* stats1 = stats, *stats2 = stats + 192;

  k0_init<<<432, 256, 0, stream>>>(As, Bs, Ar, Wm, Wo, ABsw, Wsw, Wosw, stats);
  k1r<<<NB * TB, 384, 0, stream>>>(x, ABsw, Wsw, bm, HR, stats1);
  k3n<<<NB * TB / 2, 384, 0, stream>>>(HR, stats1, g1, bt1, Wosw, bo, out_pre, stats2);
  k5_bn2<<<(NB * CB * TB * VB / 4 + 255) / 256, 256, 0, stream>>>(out_pre, stats2, g2, bt2, out);
}

// Round 10
// 234.734 us; speedup vs baseline: 1.1461x; 1.0648x over previous
//
#include <hip/hip_runtime.h>

// MS-G3D block. Fused bf16-MFMA k1: pre-swizzled unfold (XUT), swizzled weights,
// cross-ps register pipeline, bpermute C->B transform. No barriers in ps loop.
// N=8, C=96, T=128, V=25, WIN=3, VL=75, NS=6.

#define NB 8
#define CB 96
#define TB 128
#define VB 25
#define VLB 75
#define EPSB 1e-5f
#define HBS 296   // hnb row stride (shorts)
#define HRS 80    // h_relu row stride (shorts)

typedef __attribute__((ext_vector_type(8))) short bf16x8;
typedef __attribute__((ext_vector_type(4))) float f32x4;

__device__ inline unsigned short f2bf(float f) {
  unsigned int u = __float_as_uint(f);
  u = (u + 0x7FFFu + ((u >> 16) & 1u)) >> 16;
  return (unsigned short)u;
}
__device__ inline float bf2f(unsigned short u) {
  return __uint_as_float(((unsigned int)u) << 16);
}
__device__ inline unsigned int pack2(float lo, float hi) {
  unsigned int a = __float_as_uint(hi) + 0x8000u;
  unsigned int b = __float_as_uint(lo) + 0x8000u;
  return __builtin_amdgcn_perm(a, b, 0x07060302u);
}

// ---------------- K0: fragment-swizzled weights; zero stats ------------------
__global__ __launch_bounds__(256) void k0_init(
    const float* __restrict__ As, const float* __restrict__ Bs,
    const float* __restrict__ Ar, const float* __restrict__ Wm,
    const float* __restrict__ Wo,
    unsigned short* __restrict__ ABsw, unsigned short* __restrict__ Wsw,
    unsigned short* __restrict__ Wosw, float* __restrict__ stats) {
  int i = blockIdx.x * 256 + threadIdx.x;
  if (i < 110592) {                     // Wsw: 12*6*3*512
    int ps = i / 9216, r = i % 9216;
    int wv = r / 1536, r2 = r % 1536;
    int kk = r2 / 512, r3 = r2 % 512;
    int lane = r3 / 8, j = r3 % 8;
    int o = wv * 16 + (lane & 15);
    int c = kk * 32 + (lane >> 4) * 8 + j;
    Wsw[i] = f2bf(Wm[o * 1152 + ps * 96 + c]);
  }
  if (i < 92160) {                      // ABsw: 12*5*3*512
    int ps = i / 7680, r = i % 7680;
    int ut = r / 1536, r2 = r % 1536;
    int kk = r2 / 512, r3 = r2 % 512;
    int lane = r3 / 8, j = r3 % 8;
    int u = ut * 16 + (lane & 15);
    int up = kk * 32 + (lane >> 4) * 8 + j;
    float v = 0.f;
    if (u < 75 && up < 75) {
      int path = ps / 6, s = ps % 6;
      int idx = (s * 75 + u) * 75 + up;
      v = (path == 0 ? As[idx] : Bs[idx]) + Ar[idx];
    }
    ABsw[i] = f2bf(v);
  }
  if (i < 27648) {                      // Wosw: 6*9*512
    int wv = i / 4608, r = i % 4608;
    int kk = r / 512, r3 = r % 512;
    int lane = r3 / 8, j = r3 % 8;
    int o = wv * 16 + (lane & 15);
    int k = kk * 32 + (lane >> 4) * 8 + j;
    Wosw[i] = f2bf(Wo[o * 288 + k]);
  }
  if (i < 384) stats[i] = 0.f;
}

// ---------------- KP2: unfold x -> XUT in A-fragment order -------------------
// XUT[nt][fi=(ut*3+kk)][lane][j] = xu[u'=ut*16+(lane&15)][c=kk*32+(lane>>4)*8+j]
__global__ __launch_bounds__(256) void kp2(
    const float* __restrict__ x, unsigned short* __restrict__ XUT) {
  __shared__ float xs[96][81];
  const int tid = threadIdx.x;
  const int nt = blockIdx.x, n = nt >> 7, t = nt & 127;
  for (int idx = tid; idx < 96 * 75; idx += 256) {
    int c = idx / 75, rv = idx - c * 75;
    int w = rv / 25, v = rv % 25, tt = t - 1 + w;
    xs[c][rv] = (tt >= 0 && tt < TB) ? x[((n * CB + c) * TB + tt) * VB + v] : 0.f;
  }
  __syncthreads();
  for (int idx = tid; idx < 7680; idx += 256) {
    int lane = (idx >> 3) & 63, j = idx & 7, fi = idx >> 9;
    int ut = fi / 3, kk = fi - ut * 3;
    int up = ut * 16 + (lane & 15);
    int c = kk * 32 + ((lane >> 4) << 3) + j;
    XUT[nt * 7680 + idx] = f2bf(up < 75 ? xs[c][up] : 0.f);
  }
}

// ---------------- K1: fused (MLP^T -> bpermute -> agg^T) x12, pipelined ------
// grid = N*T = 1024, 384 thr (6 waves). Wave w owns o-cols [16w,16w+16).
__global__ __launch_bounds__(384, 3) void k1v(
    const unsigned short* __restrict__ XUT, const unsigned short* __restrict__ ABsw,
    const unsigned short* __restrict__ Wsw, const float* __restrict__ bm,
    unsigned short* __restrict__ h_relu, float* __restrict__ stats1) {
  __shared__ unsigned short xfrag[7680];     // frag-ordered xu slab (15.4 KB)
  __shared__ float st1s[96], st2s[96];
  const int tid = threadIdx.x;
  const int nt = blockIdx.x, n = nt >> 7, t = nt & 127;
  const int wave = tid >> 6, lane = tid & 63;
  const int l15 = lane & 15, quad = lane >> 4;

  // staging: straight vector copy, coalesced, no arithmetic
  {
    const bf16x8* src = reinterpret_cast<const bf16x8*>(XUT + nt * 7680);
    bf16x8* dst = reinterpret_cast<bf16x8*>(xfrag);
    for (int i = tid; i < 960; i += 384) dst[i] = src[i];
  }
  __syncthreads();

  const f32x4 zf = {0.f, 0.f, 0.f, 0.f};
  f32x4 acc2[5];
#pragma unroll
  for (int ut = 0; ut < 5; ++ut) acc2[ut] = zf;

  const unsigned short* Wbase = Wsw + wave * 1536 + lane * 8;
  const unsigned short* Bbase = ABsw + lane * 8;
  const unsigned short* Xb = xfrag + lane * 8;
  const int srcA = ((2 * (quad & 1)) * 16 + l15) * 4;
  const int srcB = ((2 * (quad & 1) + 1) * 16 + l15) * 4;
  const bool hiq = (quad >> 1) != 0;

  bf16x8 wa[3], wan[3];
#pragma unroll
  for (int kk = 0; kk < 3; ++kk)
    wa[kk] = *reinterpret_cast<const bf16x8*>(Wbase + kk * 512);

#pragma unroll
  for (int ps = 0; ps < 12; ++ps) {
    // issue first AB kk-group early (covers pack+bperm phase)
    bf16x8 abc[5], abn[5];
#pragma unroll
    for (int i = 0; i < 5; ++i)
      abc[i] = *reinterpret_cast<const bf16x8*>(Bbase + ps * 7680 + (i * 3) * 512);

    // GEMM1 transposed: D'[u'][o] = sum_c xu[u'][c] * W[c][o]  (LDS A, reg B)
    f32x4 acc1[5];
#pragma unroll
    for (int ut = 0; ut < 5; ++ut) acc1[ut] = zf;
#pragma unroll
    for (int kk = 0; kk < 3; ++kk)
#pragma unroll
      for (int ut = 0; ut < 5; ++ut) {
        bf16x8 xa = *reinterpret_cast<const bf16x8*>(Xb + (ut * 3 + kk) * 512);
        acc1[ut] = __builtin_amdgcn_mfma_f32_16x16x32_bf16(xa, wa[kk], acc1[ut], 0, 0, 0);
      }
    // prefetch next ps's W frags (hidden behind pack+bperm+GEMM2)
    if (ps < 11) {
#pragma unroll
      for (int kk = 0; kk < 3; ++kk)
        wan[kk] = *reinterpret_cast<const bf16x8*>(Wbase + (ps + 1) * 9216 + kk * 512);
    }
    // pack C-layout pairs into dwords
    int dw[5][2];
#pragma unroll
    for (int ut = 0; ut < 5; ++ut) {
      dw[ut][0] = pack2(acc1[ut][0], acc1[ut][1]);
      dw[ut][1] = pack2(acc1[ut][2], acc1[ut][3]);
    }
    // GEMM2: D2[u][o] += AB[u][u'] * tmp'[u'][o]; B2 via bpermute; AB kk-prefetch
#pragma unroll
    for (int kk = 0; kk < 3; ++kk) {
      if (kk < 2) {
#pragma unroll
        for (int i = 0; i < 5; ++i)
          abn[i] = *reinterpret_cast<const bf16x8*>(Bbase + ps * 7680 + (i * 3 + kk + 1) * 512);
      }
      int bi[4];
#pragma unroll
      for (int w = 0; w < 4; ++w) {
        int src = (w < 2) ? srcA : srcB;
        int rA = __builtin_amdgcn_ds_bpermute(src, dw[2 * kk][w & 1]);
        int rB = (kk < 2) ? __builtin_amdgcn_ds_bpermute(src, dw[2 * kk + 1][w & 1]) : 0;
        bi[w] = hiq ? rB : rA;
      }
      bf16x8 b2 = *reinterpret_cast<bf16x8*>(bi);
#pragma unroll
      for (int ut = 0; ut < 5; ++ut)
        acc2[ut] = __builtin_amdgcn_mfma_f32_16x16x32_bf16(abc[ut], b2, acc2[ut], 0, 0, 0);
      if (kk < 2) {
#pragma unroll
        for (int i = 0; i < 5; ++i) abc[i] = abn[i];
      }
    }
#pragma unroll
    for (int kk = 0; kk < 3; ++kk) wa[kk] = wan[kk];
  }

  // epilogue: bias+relu+vec store (stride-80 rows) + BN1 stats
  const int o = wave * 16 + l15;
  const float bias = bm[o];
  unsigned short* hp = h_relu + ((n * CB + o) * TB + t) * HRS;
  float s1 = 0.f, s2 = 0.f;
#pragma unroll
  for (int ut = 0; ut < 5; ++ut) {
    float vr[4];
#pragma unroll
    for (int r = 0; r < 4; ++r) {
      float v = acc2[ut][r] + bias;
      vr[r] = v > 0.f ? v : 0.f;
      int u = ut * 16 + quad * 4 + r;
      if (u < VLB) { s1 += vr[r]; s2 += vr[r] * vr[r]; }
    }
    *reinterpret_cast<uint2*>(hp + ut * 16 + quad * 4) =
        make_uint2(pack2(vr[0], vr[1]), pack2(vr[2], vr[3]));
  }
  s1 += __shfl_xor(s1, 16, 64); s2 += __shfl_xor(s2, 16, 64);
  s1 += __shfl_xor(s1, 32, 64); s2 += __shfl_xor(s2, 32, 64);
  if (quad == 0) { st1s[o] = s1; st2s[o] = s2; }
  __syncthreads();
  if (tid < 96) {
    atomicAdd(&stats1[tid], st1s[tid]);
    atomicAdd(&stats1[96 + tid], st2s[tid]);
  }
}

// ---------------- K3: BN1-finalize + relu + out_conv (MFMA, 2 t/blk) --------
__global__ __launch_bounds__(384) void k3n(
    const unsigned short* __restrict__ h_relu, const float* __restrict__ stats1,
    const float* __restrict__ g1, const float* __restrict__ bt1,
    const unsigned short* __restrict__ Wosw, const float* __restrict__ bo,
    float* __restrict__ out_pre, float* __restrict__ stats2) {
  __shared__ unsigned short hnb[2][32 * HBS];
  __shared__ float a1s[96], b1s[96];
  __shared__ float st1[96], st2[96];
  const int tid = threadIdx.x;
  const int n = blockIdx.x >> 6, t0 = (blockIdx.x & 63) * 2;

  if (tid < 96) {
    const float inv = 1.f / (8.f * 128.f * 75.f);
    float m = stats1[tid] * inv;
    float var = stats1[96 + tid] * inv - m * m;
    float a = g1[tid] * rsqrtf(var + EPSB);
    a1s[tid] = a;
    b1s[tid] = bt1[tid] - m * a;
  }
  for (int idx = tid; idx < 2 * 7 * HBS; idx += 384) {
    int d = idx / (7 * HBS), rm = idx % (7 * HBS);
    hnb[d][25 * HBS + rm] = 0;
  }
  __syncthreads();

  for (int idx = tid; idx < 2 * 96 * 75; idx += 384) {
    int d = idx / 7200, rm = idx % 7200;
    int i = rm / 75, u = rm - i * 75;
    float hv = bf2f(h_relu[((n * CB + i) * TB + t0 + d) * HRS + u]);
    float v = a1s[i] * hv + b1s[i];
    v = v > 0.f ? v : 0.f;
    int w = u / 25, vv = u - w * 25;
    hnb[d][vv * HBS + i * 3 + w] = f2bf(v);
  }
  __syncthreads();

  const int wave = tid >> 6, lane = tid & 63;
  const int l15 = lane & 15, quad = lane >> 4, q8 = quad * 8;
  const f32x4 zf = {0.f, 0.f, 0.f, 0.f};
  f32x4 acc[2][2] = {{zf, zf}, {zf, zf}};
  const unsigned short* Apw = Wosw + wave * 4608 + lane * 8;
#pragma unroll
  for (int kk = 0; kk < 9; ++kk) {
    bf16x8 a = *reinterpret_cast<const bf16x8*>(Apw + kk * 512);
#pragma unroll
    for (int d = 0; d < 2; ++d) {
      bf16x8 b0 = *reinterpret_cast<const bf16x8*>(&hnb[d][l15 * HBS + kk * 32 + q8]);
      bf16x8 b1 = *reinterpret_cast<const bf16x8*>(&hnb[d][(16 + l15) * HBS + kk * 32 + q8]);
      acc[d][0] = __builtin_amdgcn_mfma_f32_16x16x32_bf16(a, b0, acc[d][0], 0, 0, 0);
      acc[d][1] = __builtin_amdgcn_mfma_f32_16x16x32_bf16(a, b1, acc[d][1], 0, 0, 0);
    }
  }

  const int orow = wave * 16 + quad * 4;
  float s1[4] = {0.f, 0.f, 0.f, 0.f}, s2[4] = {0.f, 0.f, 0.f, 0.f};
#pragma unroll
  for (int d = 0; d < 2; ++d) {
#pragma unroll
    for (int ntl = 0; ntl < 2; ++ntl) {
      int v = ntl * 16 + l15;
      if (v < VB) {
#pragma unroll
        for (int r = 0; r < 4; ++r) {
          const int o = orow + r;
          float val = acc[d][ntl][r] + bo[o];
          out_pre[((n * CB + o) * TB + t0 + d) * VB + v] = val;
          s1[r] += val;
          s2[r] += val * val;
        }
      }
    }
  }
#pragma unroll
  for (int off = 1; off < 16; off <<= 1) {
#pragma unroll
    for (int r = 0; r < 4; ++r) {
      s1[r] += __shfl_xor(s1[r], off, 64);
      s2[r] += __shfl_xor(s2[r], off, 64);
    }
  }
  if (l15 == 0) {
#pragma unroll
    for (int r = 0; r < 4; ++r) { st1[orow + r] = s1[r]; st2[orow + r] = s2[r]; }
  }
  __syncthreads();
  if (tid < 96) {
    atomicAdd(&stats2[tid], st1[tid]);
    atomicAdd(&stats2[96 + tid], st2[tid]);
  }
}

// ---------------- K5: BN2 finalize (float4 elementwise) ----------------
__global__ __launch_bounds__(256) void k5_bn2(
    const float* __restrict__ out_pre, const float* __restrict__ stats2,
    const float* __restrict__ g2, const float* __restrict__ bt2,
    float* __restrict__ out) {
  int idx = blockIdx.x * 256 + threadIdx.x;
  if (idx >= NB * CB * TB * VB / 4) return;
  int o = (idx / (TB * VB / 4)) % CB;
  const float inv = 1.f / (8.f * 128.f * 25.f);
  float m = stats2[o] * inv;
  float var = stats2[96 + o] * inv - m * m;
  float a = g2[o] * rsqrtf(var + EPSB);
  float b = bt2[o] - m * a;
  f32x4 vin = reinterpret_cast<const f32x4*>(out_pre)[idx];
  f32x4 vo;
#pragma unroll
  for (int j = 0; j < 4; ++j) vo[j] = a * vin[j] + b;
  reinterpret_cast<f32x4*>(out)[idx] = vo;
}

extern "C" void kernel_launch(void* const* d_in, const int* in_sizes, int n_in,
                              void* d_out, int out_size, void* d_ws, size_t ws_size,
                              hipStream_t stream) {
  const float* x   = (const float*)d_in[0];
  const float* As  = (const float*)d_in[1];
  const float* Bs  = (const float*)d_in[2];
  const float* Ar  = (const float*)d_in[3];
  const float* Wm  = (const float*)d_in[4];
  const float* bm  = (const float*)d_in[5];
  const float* g1  = (const float*)d_in[6];
  const float* bt1 = (const float*)d_in[7];
  const float* Wo  = (const float*)d_in[8];
  const float* bo  = (const float*)d_in[9];
  const float* g2  = (const float*)d_in[10];
  const float* bt2 = (const float*)d_in[11];
  float* out = (float*)d_out;

  char* base = (char*)d_ws;
  unsigned short* XUT  = (unsigned short*)base;                  // 15,728,640 B
  unsigned short* HR   = (unsigned short*)(base + 15728640);     // 15,728,640 B
  float* out_pre       = (float*)(base + 31457280);              //  9,830,400 B
  unsigned short* ABsw = (unsigned short*)(base + 41287680);     //    184,320 B
  unsigned short* Wsw  = (unsigned short*)(base + 41472000);     //    221,184 B
  unsigned short* Wosw = (unsigned short*)(base + 41693184);     //     55,296 B
  float* stats         = (float*)(base + 41748480);              //      1,536 B
  float* stats1 = stats, *stats2 = stats + 192;

  k0_init<<<432, 256, 0, stream>>>(As, Bs, Ar, Wm, Wo, ABsw, Wsw, Wosw, stats);
  kp2<<<NB * TB, 256, 0, stream>>>(x, XUT);
  k1v<<<NB * TB, 384, 0, stream>>>(XUT, ABsw, Wsw, bm, HR, stats1);
  k3n<<<NB * TB / 2, 384, 0, stream>>>(HR, stats1, g1, bt1, Wosw, bo, out_pre, stats2);
  k5_bn2<<<(NB * CB * TB * VB / 4 + 255) / 256, 256, 0, stream>>>(out_pre, stats2, g2, bt2, out);
}

// Round 11
// 226.815 us; speedup vs baseline: 1.1861x; 1.0349x over previous
//
#include <hip/hip_runtime.h>

// MS-G3D block. k1: register-resident x fragments (no LDS staging, no barriers),
// swizzled weights, cross-ps prefetch, bpermute C->B transform.
// N=8, C=96, T=128, V=25, WIN=3, VL=75, NS=6.

#define NB 8
#define CB 96
#define TB 128
#define VB 25
#define VLB 75
#define EPSB 1e-5f
#define HBS 296   // hnb row stride (shorts)
#define HRS 80    // h_relu row stride (shorts)

typedef __attribute__((ext_vector_type(8))) short bf16x8;
typedef __attribute__((ext_vector_type(4))) float f32x4;

__device__ inline unsigned short f2bf(float f) {
  unsigned int u = __float_as_uint(f);
  u = (u + 0x7FFFu + ((u >> 16) & 1u)) >> 16;
  return (unsigned short)u;
}
__device__ inline float bf2f(unsigned short u) {
  return __uint_as_float(((unsigned int)u) << 16);
}
__device__ inline unsigned int pack2(float lo, float hi) {
  unsigned int a = __float_as_uint(hi) + 0x8000u;
  unsigned int b = __float_as_uint(lo) + 0x8000u;
  return __builtin_amdgcn_perm(a, b, 0x07060302u);
}

// ---------------- K0: fragment-swizzled weights; zero stats ------------------
__global__ __launch_bounds__(256) void k0_init(
    const float* __restrict__ As, const float* __restrict__ Bs,
    const float* __restrict__ Ar, const float* __restrict__ Wm,
    const float* __restrict__ Wo,
    unsigned short* __restrict__ ABsw, unsigned short* __restrict__ Wsw,
    unsigned short* __restrict__ Wosw, float* __restrict__ stats) {
  int i = blockIdx.x * 256 + threadIdx.x;
  if (i < 110592) {                     // Wsw: 12*6*3*512
    int ps = i / 9216, r = i % 9216;
    int wv = r / 1536, r2 = r % 1536;
    int kk = r2 / 512, r3 = r2 % 512;
    int lane = r3 / 8, j = r3 % 8;
    int o = wv * 16 + (lane & 15);
    int c = kk * 32 + (lane >> 4) * 8 + j;
    Wsw[i] = f2bf(Wm[o * 1152 + ps * 96 + c]);
  }
  if (i < 92160) {                      // ABsw: 12*5*3*512
    int ps = i / 7680, r = i % 7680;
    int ut = r / 1536, r2 = r % 1536;
    int kk = r2 / 512, r3 = r2 % 512;
    int lane = r3 / 8, j = r3 % 8;
    int u = ut * 16 + (lane & 15);
    int up = kk * 32 + (lane >> 4) * 8 + j;
    float v = 0.f;
    if (u < 75 && up < 75) {
      int path = ps / 6, s = ps % 6;
      int idx = (s * 75 + u) * 75 + up;
      v = (path == 0 ? As[idx] : Bs[idx]) + Ar[idx];
    }
    ABsw[i] = f2bf(v);
  }
  if (i < 27648) {                      // Wosw: 6*9*512
    int wv = i / 4608, r = i % 4608;
    int kk = r / 512, r3 = r % 512;
    int lane = r3 / 8, j = r3 % 8;
    int o = wv * 16 + (lane & 15);
    int k = kk * 32 + (lane >> 4) * 8 + j;
    Wosw[i] = f2bf(Wo[o * 288 + k]);
  }
  if (i < 384) stats[i] = 0.f;
}

// ---------------- KP2: unfold x -> XUT in A-fragment order -------------------
__global__ __launch_bounds__(256) void kp2(
    const float* __restrict__ x, unsigned short* __restrict__ XUT) {
  __shared__ float xs[96][81];
  const int tid = threadIdx.x;
  const int nt = blockIdx.x, n = nt >> 7, t = nt & 127;
  for (int idx = tid; idx < 96 * 75; idx += 256) {
    int c = idx / 75, rv = idx - c * 75;
    int w = rv / 25, v = rv % 25, tt = t - 1 + w;
    xs[c][rv] = (tt >= 0 && tt < TB) ? x[((n * CB + c) * TB + tt) * VB + v] : 0.f;
  }
  __syncthreads();
  for (int idx = tid; idx < 7680; idx += 256) {
    int lane = (idx >> 3) & 63, j = idx & 7, fi = idx >> 9;
    int ut = fi / 3, kk = fi - ut * 3;
    int up = ut * 16 + (lane & 15);
    int c = kk * 32 + ((lane >> 4) << 3) + j;
    XUT[nt * 7680 + idx] = f2bf(up < 75 ? xs[c][up] : 0.f);
  }
}

// ---------------- K1: register-resident x frags, pipelined, no barriers ------
// grid = N*T = 1024, 384 thr (6 waves). Wave w owns o-cols [16w,16w+16).
__global__ __launch_bounds__(384) void k1w(
    const unsigned short* __restrict__ XUT, const unsigned short* __restrict__ ABsw,
    const unsigned short* __restrict__ Wsw, const float* __restrict__ bm,
    unsigned short* __restrict__ h_relu, float* __restrict__ stats1) {
  __shared__ float st1s[96], st2s[96];
  const int tid = threadIdx.x;
  const int nt = blockIdx.x, n = nt >> 7, t = nt & 127;
  const int wave = tid >> 6, lane = tid & 63;
  const int l15 = lane & 15, quad = lane >> 4;

  // x fragments: load once, coalesced, reused across all 12 ps
  bf16x8 xa[15];
  {
    const unsigned short* Xb = XUT + nt * 7680 + lane * 8;
#pragma unroll
    for (int i = 0; i < 15; ++i)
      xa[i] = *reinterpret_cast<const bf16x8*>(Xb + i * 512);
  }

  const f32x4 zf = {0.f, 0.f, 0.f, 0.f};
  f32x4 acc2[5];
#pragma unroll
  for (int ut = 0; ut < 5; ++ut) acc2[ut] = zf;

  const unsigned short* Wbase = Wsw + wave * 1536 + lane * 8;
  const unsigned short* Bbase = ABsw + lane * 8;
  const int srcA = ((2 * (quad & 1)) * 16 + l15) * 4;
  const int srcB = ((2 * (quad & 1) + 1) * 16 + l15) * 4;
  const bool hiq = (quad >> 1) != 0;

  bf16x8 wa[3], wan[3];
#pragma unroll
  for (int kk = 0; kk < 3; ++kk)
    wa[kk] = *reinterpret_cast<const bf16x8*>(Wbase + kk * 512);

#pragma unroll
  for (int ps = 0; ps < 12; ++ps) {
    bf16x8 abc[5], abn[5];
#pragma unroll
    for (int i = 0; i < 5; ++i)
      abc[i] = *reinterpret_cast<const bf16x8*>(Bbase + ps * 7680 + (i * 3) * 512);

    // GEMM1 transposed: pure register MFMA burst
    f32x4 acc1[5];
#pragma unroll
    for (int ut = 0; ut < 5; ++ut) acc1[ut] = zf;
#pragma unroll
    for (int kk = 0; kk < 3; ++kk)
#pragma unroll
      for (int ut = 0; ut < 5; ++ut)
        acc1[ut] = __builtin_amdgcn_mfma_f32_16x16x32_bf16(xa[ut * 3 + kk], wa[kk], acc1[ut], 0, 0, 0);
    if (ps < 11) {
#pragma unroll
      for (int kk = 0; kk < 3; ++kk)
        wan[kk] = *reinterpret_cast<const bf16x8*>(Wbase + (ps + 1) * 9216 + kk * 512);
    }
    int dw[5][2];
#pragma unroll
    for (int ut = 0; ut < 5; ++ut) {
      dw[ut][0] = pack2(acc1[ut][0], acc1[ut][1]);
      dw[ut][1] = pack2(acc1[ut][2], acc1[ut][3]);
    }
#pragma unroll
    for (int kk = 0; kk < 3; ++kk) {
      if (kk < 2) {
#pragma unroll
        for (int i = 0; i < 5; ++i)
          abn[i] = *reinterpret_cast<const bf16x8*>(Bbase + ps * 7680 + (i * 3 + kk + 1) * 512);
      }
      int bi[4];
#pragma unroll
      for (int w = 0; w < 4; ++w) {
        int src = (w < 2) ? srcA : srcB;
        int rA = __builtin_amdgcn_ds_bpermute(src, dw[2 * kk][w & 1]);
        int rB = (kk < 2) ? __builtin_amdgcn_ds_bpermute(src, dw[2 * kk + 1][w & 1]) : 0;
        bi[w] = hiq ? rB : rA;
      }
      bf16x8 b2 = *reinterpret_cast<bf16x8*>(bi);
#pragma unroll
      for (int ut = 0; ut < 5; ++ut)
        acc2[ut] = __builtin_amdgcn_mfma_f32_16x16x32_bf16(abc[ut], b2, acc2[ut], 0, 0, 0);
      if (kk < 2) {
#pragma unroll
        for (int i = 0; i < 5; ++i) abc[i] = abn[i];
      }
    }
#pragma unroll
    for (int kk = 0; kk < 3; ++kk) wa[kk] = wan[kk];
  }

  // epilogue: bias+relu+vec store (stride-80 rows) + BN1 stats
  const int o = wave * 16 + l15;
  const float bias = bm[o];
  unsigned short* hp = h_relu + ((n * CB + o) * TB + t) * HRS;
  float s1 = 0.f, s2 = 0.f;
#pragma unroll
  for (int ut = 0; ut < 5; ++ut) {
    float vr[4];
#pragma unroll
    for (int r = 0; r < 4; ++r) {
      float v = acc2[ut][r] + bias;
      vr[r] = v > 0.f ? v : 0.f;
      int u = ut * 16 + quad * 4 + r;
      if (u < VLB) { s1 += vr[r]; s2 += vr[r] * vr[r]; }
    }
    *reinterpret_cast<uint2*>(hp + ut * 16 + quad * 4) =
        make_uint2(pack2(vr[0], vr[1]), pack2(vr[2], vr[3]));
  }
  s1 += __shfl_xor(s1, 16, 64); s2 += __shfl_xor(s2, 16, 64);
  s1 += __shfl_xor(s1, 32, 64); s2 += __shfl_xor(s2, 32, 64);
  if (quad == 0) { st1s[o] = s1; st2s[o] = s2; }
  __syncthreads();
  if (tid < 96) {
    atomicAdd(&stats1[tid], st1s[tid]);
    atomicAdd(&stats1[96 + tid], st2s[tid]);
  }
}

// ---------------- K3: BN1-finalize + relu + out_conv (MFMA, 2 t/blk) --------
// staging: thread <-> (half,d,i) row map, bf16x8 vector loads, no integer div.
__global__ __launch_bounds__(384) void k3n(
    const unsigned short* __restrict__ h_relu, const float* __restrict__ stats1,
    const float* __restrict__ g1, const float* __restrict__ bt1,
    const unsigned short* __restrict__ Wosw, const float* __restrict__ bo,
    float* __restrict__ out_pre, float* __restrict__ stats2) {
  __shared__ unsigned short hnb[2][32 * HBS];
  __shared__ float a1s[96], b1s[96];
  __shared__ float st1[96], st2[96];
  const int tid = threadIdx.x;
  const int n = blockIdx.x >> 6, t0 = (blockIdx.x & 63) * 2;

  if (tid < 96) {
    const float inv = 1.f / (8.f * 128.f * 75.f);
    float m = stats1[tid] * inv;
    float var = stats1[96 + tid] * inv - m * m;
    float a = g1[tid] * rsqrtf(var + EPSB);
    a1s[tid] = a;
    b1s[tid] = bt1[tid] - m * a;
  }
  for (int idx = tid; idx < 2 * 7 * HBS; idx += 384) {
    int d = idx / (7 * HBS), rm = idx % (7 * HBS);
    hnb[d][25 * HBS + rm] = 0;
  }
  __syncthreads();

  // staging: half = tid/192 (wave-uniform), row = tid%192 -> (d, i)
  {
    const int half = tid / 192, row = tid % 192;
    const int d = row >= 96, i = row - d * 96;
    const unsigned short* src = h_relu + ((n * CB + i) * TB + t0 + d) * HRS + half * 40;
    const float a1 = a1s[i], b1 = b1s[i];
    bf16x8 hbuf[5];
#pragma unroll
    for (int k = 0; k < 5; ++k)
      hbuf[k] = *reinterpret_cast<const bf16x8*>(src + k * 8);
    unsigned short* dst = &hnb[d][0] + i * 3;
    if (half == 0) {
      // u = k*8+j in [0,40): w=0 (u<25) or w=1
#pragma unroll
      for (int k = 0; k < 5; ++k)
#pragma unroll
        for (int j = 0; j < 8; ++j) {
          const int u = k * 8 + j;
          const int w = u / 25, v = u - w * 25;   // compile-time
          float hv = a1 * bf2f((unsigned short)hbuf[k][j]) + b1;
          dst[v * HBS + w] = f2bf(hv > 0.f ? hv : 0.f);
        }
    } else {
      // u = 40+k*8+j in [40,75): w=1 or 2 (skip u>=75)
#pragma unroll
      for (int k = 0; k < 5; ++k)
#pragma unroll
        for (int j = 0; j < 8; ++j) {
          const int u = 40 + k * 8 + j;
          if (u < VLB) {
            const int w = u / 25, v = u - w * 25;  // compile-time
            float hv = a1 * bf2f((unsigned short)hbuf[k][j]) + b1;
            dst[v * HBS + w] = f2bf(hv > 0.f ? hv : 0.f);
          }
        }
    }
  }
  __syncthreads();

  const int wave = tid >> 6, lane = tid & 63;
  const int l15 = lane & 15, quad = lane >> 4, q8 = quad * 8;
  const f32x4 zf = {0.f, 0.f, 0.f, 0.f};
  f32x4 acc[2][2] = {{zf, zf}, {zf, zf}};
  const unsigned short* Apw = Wosw + wave * 4608 + lane * 8;
#pragma unroll
  for (int kk = 0; kk < 9; ++kk) {
    bf16x8 a = *reinterpret_cast<const bf16x8*>(Apw + kk * 512);
#pragma unroll
    for (int d = 0; d < 2; ++d) {
      bf16x8 b0 = *reinterpret_cast<const bf16x8*>(&hnb[d][l15 * HBS + kk * 32 + q8]);
      bf16x8 b1 = *reinterpret_cast<const bf16x8*>(&hnb[d][(16 + l15) * HBS + kk * 32 + q8]);
      acc[d][0] = __builtin_amdgcn_mfma_f32_16x16x32_bf16(a, b0, acc[d][0], 0, 0, 0);
      acc[d][1] = __builtin_amdgcn_mfma_f32_16x16x32_bf16(a, b1, acc[d][1], 0, 0, 0);
    }
  }

  const int orow = wave * 16 + quad * 4;
  float s1[4] = {0.f, 0.f, 0.f, 0.f}, s2[4] = {0.f, 0.f, 0.f, 0.f};
#pragma unroll
  for (int d = 0; d < 2; ++d) {
#pragma unroll
    for (int ntl = 0; ntl < 2; ++ntl) {
      int v = ntl * 16 + l15;
      if (v < VB) {
#pragma unroll
        for (int r = 0; r < 4; ++r) {
          const int o = orow + r;
          float val = acc[d][ntl][r] + bo[o];
          out_pre[((n * CB + o) * TB + t0 + d) * VB + v] = val;
          s1[r] += val;
          s2[r] += val * val;
        }
      }
    }
  }
#pragma unroll
  for (int off = 1; off < 16; off <<= 1) {
#pragma unroll
    for (int r = 0; r < 4; ++r) {
      s1[r] += __shfl_xor(s1[r], off, 64);
      s2[r] += __shfl_xor(s2[r], off, 64);
    }
  }
  if (l15 == 0) {
#pragma unroll
    for (int r = 0; r < 4; ++r) { st1[orow + r] = s1[r]; st2[orow + r] = s2[r]; }
  }
  __syncthreads();
  if (tid < 96) {
    atomicAdd(&stats2[tid], st1[tid]);
    atomicAdd(&stats2[96 + tid], st2[tid]);
  }
}

// ---------------- K5: BN2 finalize (float4 elementwise) ----------------
__global__ __launch_bounds__(256) void k5_bn2(
    const float* __restrict__ out_pre, const float* __restrict__ stats2,
    const float* __restrict__ g2, const float* __restrict__ bt2,
    float* __restrict__ out) {
  int idx = blockIdx.x * 256 + threadIdx.x;
  if (idx >= NB * CB * TB * VB / 4) return;
  int o = (idx / (TB * VB / 4)) % CB;
  const float inv = 1.f / (8.f * 128.f * 25.f);
  float m = stats2[o] * inv;
  float var = stats2[96 + o] * inv - m * m;
  float a = g2[o] * rsqrtf(var + EPSB);
  float b = bt2[o] - m * a;
  f32x4 vin = reinterpret_cast<const f32x4*>(out_pre)[idx];
  f32x4 vo;
#pragma unroll
  for (int j = 0; j < 4; ++j) vo[j] = a * vin[j] + b;
  reinterpret_cast<f32x4*>(out)[idx] = vo;
}

extern "C" void kernel_launch(void* const* d_in, const int* in_sizes, int n_in,
                              void* d_out, int out_size, void* d_ws, size_t ws_size,
                              hipStream_t stream) {
  const float* x   = (const float*)d_in[0];
  const float* As  = (const float*)d_in[1];
  const float* Bs  = (const float*)d_in[2];
  const float* Ar  = (const float*)d_in[3];
  const float* Wm  = (const float*)d_in[4];
  const float* bm  = (const float*)d_in[5];
  const float* g1  = (const float*)d_in[6];
  const float* bt1 = (const float*)d_in[7];
  const float* Wo  = (const float*)d_in[8];
  const float* bo  = (const float*)d_in[9];
  const float* g2  = (const float*)d_in[10];
  const float* bt2 = (const float*)d_in[11];
  float* out = (float*)d_out;

  char* base = (char*)d_ws;
  unsigned short* XUT  = (unsigned short*)base;                  // 15,728,640 B
  unsigned short* HR   = (unsigned short*)(base + 15728640);     // 15,728,640 B
  float* out_pre       = (float*)(base + 31457280);              //  9,830,400 B
  unsigned short* ABsw = (unsigned short*)(base + 41287680);     //    184,320 B
  unsigned short* Wsw  = (unsigned short*)(base + 41472000);     //    221,184 B
  unsigned short* Wosw = (unsigned short*)(base + 41693184);     //     55,296 B
  float* stats         = (float*)(base + 41748480);              //      1,536 B
  float* stats1 = stats, *stats2 = stats + 192;

  k0_init<<<432, 256, 0, stream>>>(As, Bs, Ar, Wm, Wo, ABsw, Wsw, Wosw, stats);
  kp2<<<NB * TB, 256, 0, stream>>>(x, XUT);
  k1w<<<NB * TB, 384, 0, stream>>>(XUT, ABsw, Wsw, bm, HR, stats1);
  k3n<<<NB * TB / 2, 384, 0, stream>>>(HR, stats1, g1, bt1, Wosw, bo, out_pre, stats2);
  k5_bn2<<<(NB * CB * TB * VB / 4 + 255) / 256, 256, 0, stream>>>(out_pre, stats2, g2, bt2, out);
}